// Round 3
// baseline (451.986 us; speedup 1.0000x reference)
//
#include <hip/hip_runtime.h>
#include <hip/hip_bf16.h>
#include <cstdint>
#include <cstddef>

#define NQ      14
#define SDIM    16384          // 1 << NQ
#define NGATES  39             // 3 layers * 13 fused two-qubit gates
#define NBATCH  1024

// ---------------------------------------------------------------------------
// helpers
// ---------------------------------------------------------------------------
__device__ __forceinline__ int swz(int i) { return i ^ ((i >> 4) & 15); }

__device__ __forceinline__ float2 cmul(float2 a, float2 b) {
    return make_float2(fmaf(a.x, b.x, -a.y * b.y), fmaf(a.x, b.y, a.y * b.x));
}
__device__ __forceinline__ void cfma(float2 &o, float2 a, float2 b) {
    o.x = fmaf(a.x, b.x, fmaf(-a.y, b.y, o.x));
    o.y = fmaf(a.x, b.y, fmaf( a.y, b.x, o.y));
}

__device__ void mm2(const float2 A[2][2], const float2 B[2][2], float2 C[2][2]) {
    #pragma unroll
    for (int i = 0; i < 2; ++i)
        #pragma unroll
        for (int j = 0; j < 2; ++j) {
            float2 t = cmul(A[i][0], B[0][j]);
            cfma(t, A[i][1], B[1][j]);
            C[i][j] = t;
        }
}

// U = RZ(g) * RY(b) * RX(a)  (optionally right-multiplied by encoding RY for layer 0)
__device__ void build_u(const float* __restrict__ rp, const float* __restrict__ enc,
                        int l, int q, float2 U[2][2]) {
    const float* p = rp + (l * NQ + q) * 3;
    float ha = 0.5f * p[0], hb = 0.5f * p[1], hg = 0.5f * p[2];
    float cx = cosf(ha), sx = sinf(ha);
    float cy = cosf(hb), sy = sinf(hb);
    float cz = cosf(hg), sz = sinf(hg);
    float2 RX[2][2] = { { make_float2(cx, 0.f), make_float2(0.f, -sx) },
                        { make_float2(0.f, -sx), make_float2(cx, 0.f) } };
    float2 RY[2][2] = { { make_float2(cy, 0.f), make_float2(-sy, 0.f) },
                        { make_float2(sy, 0.f), make_float2(cy, 0.f) } };
    float2 W[2][2];
    mm2(RY, RX, W);
    float2 zl = make_float2(cz, -sz), zh = make_float2(cz, sz);
    float2 V[2][2];
    V[0][0] = cmul(zl, W[0][0]); V[0][1] = cmul(zl, W[0][1]);
    V[1][0] = cmul(zh, W[1][0]); V[1][1] = cmul(zh, W[1][1]);
    if (l == 0) {   // encoding RY applied BEFORE layer-0 rotations -> right-multiply
        float he = 0.5f * enc[q];
        float ce = cosf(he), se = sinf(he);
        float2 RE[2][2] = { { make_float2(ce, 0.f), make_float2(-se, 0.f) },
                            { make_float2(se, 0.f), make_float2(ce, 0.f) } };
        mm2(V, RE, U);
    } else {
        U[0][0] = V[0][0]; U[0][1] = V[0][1];
        U[1][0] = V[1][0]; U[1][1] = V[1][1];
    }
}

// ---------------------------------------------------------------------------
// Register-window gate application. Each thread holds 16 amps = the 4-qubit
// subspace at window base AQ. Gate basis j=(t<<1)|c, c at local bit CP,
// t at local bit CP+1 (gate jj acts on qubits (jj, jj+1), CP = jj - AQ).
// ---------------------------------------------------------------------------
template<int CP>
__device__ __forceinline__ void gate_dense(float2 v[16], const float2* __restrict__ G) {
    float2 g[16];
    #pragma unroll
    for (int k = 0; k < 16; ++k) g[k] = G[k];
    #pragma unroll
    for (int rr = 0; rr < 4; ++rr) {
        const int base = ((rr >> CP) << (CP + 2)) | (rr & ((1 << CP) - 1));
        const int m0 = base, m1 = base | (1 << CP), m2 = base | (2 << CP), m3 = base | (3 << CP);
        float2 a0 = v[m0], a1 = v[m1], a2 = v[m2], a3 = v[m3];
        float2 o0 = cmul(g[0],  a0); cfma(o0, g[1],  a1); cfma(o0, g[2],  a2); cfma(o0, g[3],  a3);
        float2 o1 = cmul(g[4],  a0); cfma(o1, g[5],  a1); cfma(o1, g[6],  a2); cfma(o1, g[7],  a3);
        float2 o2 = cmul(g[8],  a0); cfma(o2, g[9],  a1); cfma(o2, g[10], a2); cfma(o2, g[11], a3);
        float2 o3 = cmul(g[12], a0); cfma(o3, g[13], a1); cfma(o3, g[14], a2); cfma(o3, g[15], a3);
        v[m0] = o0; v[m1] = o1; v[m2] = o2; v[m3] = o3;
    }
}

template<int CP>
__device__ __forceinline__ void gate_sparse(float2 v[16], const float2* __restrict__ G) {
    float2 g0 = G[0], g2 = G[2], g8 = G[8], g10 = G[10];
    float2 g5 = G[5], g7 = G[7], g13 = G[13], g15 = G[15];
    #pragma unroll
    for (int rr = 0; rr < 4; ++rr) {
        const int base = ((rr >> CP) << (CP + 2)) | (rr & ((1 << CP) - 1));
        const int m0 = base, m1 = base | (1 << CP), m2 = base | (2 << CP), m3 = base | (3 << CP);
        float2 a0 = v[m0], a1 = v[m1], a2 = v[m2], a3 = v[m3];
        float2 o0 = cmul(g0,  a0); cfma(o0, g2,  a2);
        float2 o2 = cmul(g8,  a0); cfma(o2, g10, a2);
        float2 o1 = cmul(g5,  a1); cfma(o1, g7,  a3);
        float2 o3 = cmul(g13, a1); cfma(o3, g15, a3);
        v[m0] = o0; v[m1] = o1; v[m2] = o2; v[m3] = o3;
    }
}

template<int AQ>
__device__ __forceinline__ void window_idx(int tid, int idx[16]) {
    const int i0 = ((tid >> AQ) << (AQ + 4)) | (tid & ((1 << AQ) - 1));
    #pragma unroll
    for (int j = 0; j < 16; ++j) idx[j] = swz(i0 + (j << AQ));
}

// full pass: read 16 amps, apply 3 consecutive chain gates, write back
template<int AQ, bool DENSE0>
__device__ __forceinline__ void pass3(float2* st, const float2* __restrict__ gb, int tid) {
    int idx[16];
    window_idx<AQ>(tid, idx);
    float2 v[16];
    #pragma unroll
    for (int j = 0; j < 16; ++j) v[j] = st[idx[j]];
    if (DENSE0) gate_dense<0>(v, gb); else gate_sparse<0>(v, gb);
    gate_sparse<1>(v, gb + 16);
    gate_sparse<2>(v, gb + 32);
    #pragma unroll
    for (int j = 0; j < 16; ++j) st[idx[j]] = v[j];
}

// ---------------------------------------------------------------------------
// Kernel 1: full circuit simulation, one workgroup per batch element.
// State in LDS (128 KiB, XOR-swizzled). 15 register-window passes
// (5 per layer: {0-3}g0-2, {3-6}g3-5, {6-9}g6-8, {9-12}g9-11, {10-13}g12).
// __launch_bounds__(1024, 4): one 16-wave block/CU is the LDS-imposed limit
// anyway; declaring 4 waves/EU raises the VGPR cap to 512 and prevents the
// compiler's 8-wave occupancy target from spilling v[16]/idx[16] to scratch
// (round-2 counters: 416 MB FETCH + 420 MB WRITE of pure spill traffic).
// ---------------------------------------------------------------------------
__global__ __launch_bounds__(1024, 4) void sim_kernel(
    const float* __restrict__ x,     // (1024, 64)
    const float* __restrict__ ep,    // (64, 14)
    const float* __restrict__ rp,    // (3, 14, 3)
    const float* __restrict__ ent,   // (3, 13)
    float* __restrict__ feats)       // (1024, 16384)
{
    extern __shared__ char smem[];
    float2* st     = (float2*)smem;                                   // 131072 B
    float2* gmat   = (float2*)(smem + SDIM * sizeof(float2));         // 39*16*8 = 4992 B
    float*  angles = (float*)(smem + SDIM * sizeof(float2) + NGATES * 16 * sizeof(float2));

    const int tid = threadIdx.x;
    const int b   = blockIdx.x;

    // --- encoding angles: one wave per qubit, shuffle-reduce ---
    if (tid < 14 * 64) {
        const int q = tid >> 6, k = tid & 63;
        float p = x[(size_t)b * 64 + k] * ep[k * NQ + q];
        #pragma unroll
        for (int off = 32; off; off >>= 1) p += __shfl_down(p, off, 64);
        if (k == 0) angles[q] = p;
    }
    __syncthreads();

    // --- build 39 fused 4x4 gate matrices (basis j = (t<<1)|c) ---
    if (tid < NGATES) {
        int l = tid / 13, jj = tid - l * 13;     // gate on qubits (jj, jj+1)
        float2 Ut[2][2], Uc[2][2];
        build_u(rp, angles, l, jj + 1, Ut);
        if (jj == 0) build_u(rp, angles, l, 0, Uc);
        else {
            Uc[0][0] = make_float2(1.f, 0.f); Uc[0][1] = make_float2(0.f, 0.f);
            Uc[1][0] = make_float2(0.f, 0.f); Uc[1][1] = make_float2(1.f, 0.f);
        }
        float2 T[4][4];
        #pragma unroll
        for (int j = 0; j < 4; ++j)
            #pragma unroll
            for (int jp = 0; jp < 4; ++jp)
                T[j][jp] = cmul(Ut[j >> 1][jp >> 1], Uc[j & 1][jp & 1]);
        float th = ent[l * 13 + jj];
        float ct = cosf(th), sth = sinf(th);
        float2* G = gmat + tid * 16;
        #pragma unroll
        for (int jp = 0; jp < 4; ++jp)
            #pragma unroll
            for (int t = 0; t < 2; ++t) {
                G[(t << 1) * 4 + jp] = T[t << 1][jp];
                float2 aT = T[((t << 1) | 1)][jp];
                float2 bT = T[(((1 - t) << 1) | 1)][jp];
                G[((t << 1) | 1) * 4 + jp] =
                    make_float2(fmaf(ct, aT.x, -sth * bT.y), fmaf(ct, aT.y, sth * bT.x));
            }
    }
    __syncthreads();

    #pragma unroll 1
    for (int l = 0; l < 3; ++l) {
        const float2* gl = gmat + l * 13 * 16;

        if (l == 0) {
            // pass 0: synthesize |0..0> in registers, apply gates 0,1,2, write
            int idx[16];
            window_idx<0>(tid, idx);
            float2 v[16];
            #pragma unroll
            for (int j = 0; j < 16; ++j) v[j] = make_float2(0.f, 0.f);
            if (tid == 0) v[0] = make_float2(1.f, 0.f);
            gate_dense<0>(v, gl);
            gate_sparse<1>(v, gl + 16);
            gate_sparse<2>(v, gl + 32);
            #pragma unroll
            for (int j = 0; j < 16; ++j) st[idx[j]] = v[j];
        } else {
            pass3<0, true>(st, gl, tid);
        }
        __syncthreads();
        pass3<3, false>(st, gl + 3 * 16, tid);
        __syncthreads();
        pass3<6, false>(st, gl + 6 * 16, tid);
        __syncthreads();
        pass3<9, false>(st, gl + 9 * 16, tid);
        __syncthreads();

        // w4: gate 12 on qubits (12,13); window {10-13}, CP=2
        if (l < 2) {
            int idx[16];
            window_idx<10>(tid, idx);
            float2 v[16];
            #pragma unroll
            for (int j = 0; j < 16; ++j) v[j] = st[idx[j]];
            gate_sparse<2>(v, gl + 12 * 16);
            #pragma unroll
            for (int j = 0; j < 16; ++j) st[idx[j]] = v[j];
            __syncthreads();
        } else {
            // final pass: apply gate, emit |amp|^2 straight to global (coalesced)
            int idx[16];
            window_idx<10>(tid, idx);
            float2 v[16];
            #pragma unroll
            for (int j = 0; j < 16; ++j) v[j] = st[idx[j]];
            gate_sparse<2>(v, gl + 12 * 16);
            float* fr = feats + (size_t)b * SDIM;
            #pragma unroll
            for (int j = 0; j < 16; ++j)
                fr[tid + (j << 10)] = fmaf(v[j].x, v[j].x, v[j].y * v[j].y);
        }
    }
}

// ---------------------------------------------------------------------------
// Kernel 2: GEMM1 partials: part[bz] = feats[:, bz-chunk] @ w1[bz-chunk, :]
// M=1024, N=256, K=16384 split 8 ways. 64x64 tile, 4x4 per-thread regs.
// ---------------------------------------------------------------------------
__global__ __launch_bounds__(256) void gemm1_kernel(
    const float* __restrict__ feats,   // (1024, 16384)
    const float* __restrict__ w1,      // (16384, 256)
    float* __restrict__ part)          // (8, 1024, 256)
{
    __shared__ float As[16][68];
    __shared__ float Bs[16][68];
    const int tx = threadIdx.x & 15, ty = threadIdx.x >> 4;
    const int bx = blockIdx.x, by = blockIdx.y, bz = blockIdx.z;
    const int ml = threadIdx.x >> 2;           // 0..63  (A row)
    const int kq = (threadIdx.x & 3) << 2;     // 0,4,8,12 (A k-quad)
    const int kb = threadIdx.x >> 4;           // 0..15  (B k)
    const int nb = (threadIdx.x & 15) << 2;    // 0..60  (B col quad)

    const float* Ap = feats + (size_t)(bx * 64 + ml) * SDIM + bz * 2048;
    const float* Bp = w1 + (size_t)(bz * 2048 + kb) * 256 + by * 64 + nb;

    float acc[4][4] = {{0.f}};
    for (int kt = 0; kt < 2048; kt += 16) {
        float4 av = *(const float4*)(Ap + kt + kq);
        float4 bv = *(const float4*)(Bp + (size_t)kt * 256);
        __syncthreads();
        As[kq + 0][ml] = av.x; As[kq + 1][ml] = av.y;
        As[kq + 2][ml] = av.z; As[kq + 3][ml] = av.w;
        *(float4*)&Bs[kb][nb] = bv;
        __syncthreads();
        #pragma unroll
        for (int k = 0; k < 16; ++k) {
            float4 a  = *(const float4*)&As[k][ty << 2];
            float4 b4 = *(const float4*)&Bs[k][tx << 2];
            acc[0][0] = fmaf(a.x, b4.x, acc[0][0]); acc[0][1] = fmaf(a.x, b4.y, acc[0][1]);
            acc[0][2] = fmaf(a.x, b4.z, acc[0][2]); acc[0][3] = fmaf(a.x, b4.w, acc[0][3]);
            acc[1][0] = fmaf(a.y, b4.x, acc[1][0]); acc[1][1] = fmaf(a.y, b4.y, acc[1][1]);
            acc[1][2] = fmaf(a.y, b4.z, acc[1][2]); acc[1][3] = fmaf(a.y, b4.w, acc[1][3]);
            acc[2][0] = fmaf(a.z, b4.x, acc[2][0]); acc[2][1] = fmaf(a.z, b4.y, acc[2][1]);
            acc[2][2] = fmaf(a.z, b4.z, acc[2][2]); acc[2][3] = fmaf(a.z, b4.w, acc[2][3]);
            acc[3][0] = fmaf(a.w, b4.x, acc[3][0]); acc[3][1] = fmaf(a.w, b4.y, acc[3][1]);
            acc[3][2] = fmaf(a.w, b4.z, acc[3][2]); acc[3][3] = fmaf(a.w, b4.w, acc[3][3]);
        }
    }
    float* Cp = part + ((size_t)bz * NBATCH + bx * 64 + (ty << 2)) * 256 + by * 64 + (tx << 2);
    #pragma unroll
    for (int i = 0; i < 4; ++i)
        *(float4*)(Cp + (size_t)i * 256) = make_float4(acc[i][0], acc[i][1], acc[i][2], acc[i][3]);
}

// ---------------------------------------------------------------------------
// Kernel 3: reduce split-K partials + bias + relu, then the two small GEMMs.
// ---------------------------------------------------------------------------
__global__ __launch_bounds__(256) void tail_kernel(
    const float* __restrict__ part,  // (8, 1024, 256)
    const float* __restrict__ b1,
    const float* __restrict__ w2,    // (256, 128)
    const float* __restrict__ b2,
    const float* __restrict__ w3,    // (128, 64)
    const float* __restrict__ b3,
    float* __restrict__ out)         // (1024, 64)
{
    __shared__ float h1[256];
    __shared__ float h2[128];
    const int b = blockIdx.x, t = threadIdx.x;

    float s = b1[t];
    #pragma unroll
    for (int sp = 0; sp < 8; ++sp)
        s += part[((size_t)sp * NBATCH + b) * 256 + t];
    h1[t] = fmaxf(s, 0.f);
    __syncthreads();

    if (t < 128) {
        float acc = b2[t];
        #pragma unroll 4
        for (int k = 0; k < 256; ++k) acc = fmaf(h1[k], w2[k * 128 + t], acc);
        h2[t] = fmaxf(acc, 0.f);
    }
    __syncthreads();

    if (t < 64) {
        float acc = b3[t];
        #pragma unroll 4
        for (int k = 0; k < 128; ++k) acc = fmaf(h2[k], w3[k * 64 + t], acc);
        out[(size_t)b * 64 + t] = acc;
    }
}

// ---------------------------------------------------------------------------
extern "C" void kernel_launch(void* const* d_in, const int* in_sizes, int n_in,
                              void* d_out, int out_size, void* d_ws, size_t ws_size,
                              hipStream_t stream) {
    const float* x   = (const float*)d_in[0];
    const float* ep  = (const float*)d_in[1];
    const float* rp  = (const float*)d_in[2];
    const float* ent = (const float*)d_in[3];
    const float* w1  = (const float*)d_in[4];
    const float* b1  = (const float*)d_in[5];
    const float* w2  = (const float*)d_in[6];
    const float* b2  = (const float*)d_in[7];
    const float* w3  = (const float*)d_in[8];
    const float* b3  = (const float*)d_in[9];
    float* out = (float*)d_out;

    // ws layout: feats (1024*16384 f32 = 64 MiB) | partials (8*1024*256 f32 = 8 MiB)
    float* feats = (float*)d_ws;
    float* part  = feats + (size_t)NBATCH * SDIM;

    const int SMEM = SDIM * (int)sizeof(float2) + NGATES * 16 * (int)sizeof(float2) + 64;
    (void)hipFuncSetAttribute((const void*)sim_kernel,
                              hipFuncAttributeMaxDynamicSharedMemorySize, SMEM);

    sim_kernel<<<NBATCH, 1024, SMEM, stream>>>(x, ep, rp, ent, feats);
    gemm1_kernel<<<dim3(16, 4, 8), 256, 0, stream>>>(feats, w1, part);
    tail_kernel<<<NBATCH, 256, 0, stream>>>(part, b1, w2, b2, w3, b3, out);
}

// Round 4
// 444.034 us; speedup vs baseline: 1.0179x; 1.0179x over previous
//
#include <hip/hip_runtime.h>
#include <hip/hip_bf16.h>
#include <cstdint>
#include <cstddef>

#define NQ      14
#define SDIM    16384          // 1 << NQ
#define NGATES  39             // 3 layers * 13 fused two-qubit gates
#define NBATCH  1024

// ---------------------------------------------------------------------------
// helpers
// ---------------------------------------------------------------------------
__device__ __forceinline__ int swz(int i) { return i ^ ((i >> 4) & 15); }

__device__ __forceinline__ float2 cmul(float2 a, float2 b) {
    return make_float2(fmaf(a.x, b.x, -a.y * b.y), fmaf(a.x, b.y, a.y * b.x));
}
__device__ __forceinline__ void cfma(float2 &o, float2 a, float2 b) {
    o.x = fmaf(a.x, b.x, fmaf(-a.y, b.y, o.x));
    o.y = fmaf(a.x, b.y, fmaf( a.y, b.x, o.y));
}

__device__ void mm2(const float2 A[2][2], const float2 B[2][2], float2 C[2][2]) {
    #pragma unroll
    for (int i = 0; i < 2; ++i)
        #pragma unroll
        for (int j = 0; j < 2; ++j) {
            float2 t = cmul(A[i][0], B[0][j]);
            cfma(t, A[i][1], B[1][j]);
            C[i][j] = t;
        }
}

// U = RZ(g) * RY(b) * RX(a)  (optionally right-multiplied by encoding RY for layer 0)
__device__ void build_u(const float* __restrict__ rp, const float* __restrict__ enc,
                        int l, int q, float2 U[2][2]) {
    const float* p = rp + (l * NQ + q) * 3;
    float ha = 0.5f * p[0], hb = 0.5f * p[1], hg = 0.5f * p[2];
    float cx = cosf(ha), sx = sinf(ha);
    float cy = cosf(hb), sy = sinf(hb);
    float cz = cosf(hg), sz = sinf(hg);
    float2 RX[2][2] = { { make_float2(cx, 0.f), make_float2(0.f, -sx) },
                        { make_float2(0.f, -sx), make_float2(cx, 0.f) } };
    float2 RY[2][2] = { { make_float2(cy, 0.f), make_float2(-sy, 0.f) },
                        { make_float2(sy, 0.f), make_float2(cy, 0.f) } };
    float2 W[2][2];
    mm2(RY, RX, W);
    float2 zl = make_float2(cz, -sz), zh = make_float2(cz, sz);
    float2 V[2][2];
    V[0][0] = cmul(zl, W[0][0]); V[0][1] = cmul(zl, W[0][1]);
    V[1][0] = cmul(zh, W[1][0]); V[1][1] = cmul(zh, W[1][1]);
    if (l == 0) {   // encoding RY applied BEFORE layer-0 rotations -> right-multiply
        float he = 0.5f * enc[q];
        float ce = cosf(he), se = sinf(he);
        float2 RE[2][2] = { { make_float2(ce, 0.f), make_float2(-se, 0.f) },
                            { make_float2(se, 0.f), make_float2(ce, 0.f) } };
        mm2(V, RE, U);
    } else {
        U[0][0] = V[0][0]; U[0][1] = V[0][1];
        U[1][0] = V[1][0]; U[1][1] = V[1][1];
    }
}

// ---------------------------------------------------------------------------
// Register-window gate application. Each thread holds 16 amps = the 4-qubit
// subspace at window base AQ. Gate basis j=(t<<1)|c, c at local bit CP,
// t at local bit CP+1 (gate jj acts on qubits (jj, jj+1), CP = jj - AQ).
// ---------------------------------------------------------------------------
template<int CP>
__device__ __forceinline__ void gate_dense(float2 v[16], const float2* __restrict__ G) {
    float2 g[16];
    #pragma unroll
    for (int k = 0; k < 16; ++k) g[k] = G[k];
    #pragma unroll
    for (int rr = 0; rr < 4; ++rr) {
        const int base = ((rr >> CP) << (CP + 2)) | (rr & ((1 << CP) - 1));
        const int m0 = base, m1 = base | (1 << CP), m2 = base | (2 << CP), m3 = base | (3 << CP);
        float2 a0 = v[m0], a1 = v[m1], a2 = v[m2], a3 = v[m3];
        float2 o0 = cmul(g[0],  a0); cfma(o0, g[1],  a1); cfma(o0, g[2],  a2); cfma(o0, g[3],  a3);
        float2 o1 = cmul(g[4],  a0); cfma(o1, g[5],  a1); cfma(o1, g[6],  a2); cfma(o1, g[7],  a3);
        float2 o2 = cmul(g[8],  a0); cfma(o2, g[9],  a1); cfma(o2, g[10], a2); cfma(o2, g[11], a3);
        float2 o3 = cmul(g[12], a0); cfma(o3, g[13], a1); cfma(o3, g[14], a2); cfma(o3, g[15], a3);
        v[m0] = o0; v[m1] = o1; v[m2] = o2; v[m3] = o3;
    }
}

template<int CP>
__device__ __forceinline__ void gate_sparse(float2 v[16], const float2* __restrict__ G) {
    float2 g0 = G[0], g2 = G[2], g8 = G[8], g10 = G[10];
    float2 g5 = G[5], g7 = G[7], g13 = G[13], g15 = G[15];
    #pragma unroll
    for (int rr = 0; rr < 4; ++rr) {
        const int base = ((rr >> CP) << (CP + 2)) | (rr & ((1 << CP) - 1));
        const int m0 = base, m1 = base | (1 << CP), m2 = base | (2 << CP), m3 = base | (3 << CP);
        float2 a0 = v[m0], a1 = v[m1], a2 = v[m2], a3 = v[m3];
        float2 o0 = cmul(g0,  a0); cfma(o0, g2,  a2);
        float2 o2 = cmul(g8,  a0); cfma(o2, g10, a2);
        float2 o1 = cmul(g5,  a1); cfma(o1, g7,  a3);
        float2 o3 = cmul(g13, a1); cfma(o3, g15, a3);
        v[m0] = o0; v[m1] = o1; v[m2] = o2; v[m3] = o3;
    }
}

template<int AQ>
__device__ __forceinline__ void window_idx(int tid, int idx[16]) {
    const int i0 = ((tid >> AQ) << (AQ + 4)) | (tid & ((1 << AQ) - 1));
    #pragma unroll
    for (int j = 0; j < 16; ++j) idx[j] = swz(i0 + (j << AQ));
}

// full pass: read 16 amps, apply 3 consecutive chain gates, write back
template<int AQ, bool DENSE0>
__device__ __forceinline__ void pass3(float2* st, const float2* __restrict__ gb, int tid) {
    int idx[16];
    window_idx<AQ>(tid, idx);
    float2 v[16];
    #pragma unroll
    for (int j = 0; j < 16; ++j) v[j] = st[idx[j]];
    if (DENSE0) gate_dense<0>(v, gb); else gate_sparse<0>(v, gb);
    gate_sparse<1>(v, gb + 16);
    gate_sparse<2>(v, gb + 32);
    #pragma unroll
    for (int j = 0; j < 16; ++j) st[idx[j]] = v[j];
}

// ---------------------------------------------------------------------------
// Kernel 1: full circuit simulation, one workgroup per batch element.
// State in LDS (128 KiB, XOR-swizzled). 15 register-window passes.
// amdgpu_waves_per_eu(4,4): LDS already limits us to one 16-wave block per CU
// (= 4 waves/EU). Pinning BOTH min and max stops the register allocator from
// targeting 8 waves/EU (64-VGPR cap), which was spilling ~50 regs/thread to
// scratch (r2/r3 counters: ~400 MB symmetric FETCH/WRITE spill traffic).
// Budget becomes 512/4 = 128 VGPRs; live demand ~100 fits, zero spill.
// ---------------------------------------------------------------------------
__global__ __launch_bounds__(1024) __attribute__((amdgpu_waves_per_eu(4, 4)))
void sim_kernel(
    const float* __restrict__ x,     // (1024, 64)
    const float* __restrict__ ep,    // (64, 14)
    const float* __restrict__ rp,    // (3, 14, 3)
    const float* __restrict__ ent,   // (3, 13)
    float* __restrict__ feats)       // (1024, 16384)
{
    extern __shared__ char smem[];
    float2* st     = (float2*)smem;                                   // 131072 B
    float2* gmat   = (float2*)(smem + SDIM * sizeof(float2));         // 39*16*8 = 4992 B
    float*  angles = (float*)(smem + SDIM * sizeof(float2) + NGATES * 16 * sizeof(float2));

    const int tid = threadIdx.x;
    const int b   = blockIdx.x;

    // --- encoding angles: one wave per qubit, shuffle-reduce ---
    if (tid < 14 * 64) {
        const int q = tid >> 6, k = tid & 63;
        float p = x[(size_t)b * 64 + k] * ep[k * NQ + q];
        #pragma unroll
        for (int off = 32; off; off >>= 1) p += __shfl_down(p, off, 64);
        if (k == 0) angles[q] = p;
    }
    __syncthreads();

    // --- build 39 fused 4x4 gate matrices (basis j = (t<<1)|c) ---
    if (tid < NGATES) {
        int l = tid / 13, jj = tid - l * 13;     // gate on qubits (jj, jj+1)
        float2 Ut[2][2], Uc[2][2];
        build_u(rp, angles, l, jj + 1, Ut);
        if (jj == 0) build_u(rp, angles, l, 0, Uc);
        else {
            Uc[0][0] = make_float2(1.f, 0.f); Uc[0][1] = make_float2(0.f, 0.f);
            Uc[1][0] = make_float2(0.f, 0.f); Uc[1][1] = make_float2(1.f, 0.f);
        }
        float2 T[4][4];
        #pragma unroll
        for (int j = 0; j < 4; ++j)
            #pragma unroll
            for (int jp = 0; jp < 4; ++jp)
                T[j][jp] = cmul(Ut[j >> 1][jp >> 1], Uc[j & 1][jp & 1]);
        float th = ent[l * 13 + jj];
        float ct = cosf(th), sth = sinf(th);
        float2* G = gmat + tid * 16;
        #pragma unroll
        for (int jp = 0; jp < 4; ++jp)
            #pragma unroll
            for (int t = 0; t < 2; ++t) {
                G[(t << 1) * 4 + jp] = T[t << 1][jp];
                float2 aT = T[((t << 1) | 1)][jp];
                float2 bT = T[(((1 - t) << 1) | 1)][jp];
                G[((t << 1) | 1) * 4 + jp] =
                    make_float2(fmaf(ct, aT.x, -sth * bT.y), fmaf(ct, aT.y, sth * bT.x));
            }
    }
    __syncthreads();

    #pragma unroll 1
    for (int l = 0; l < 3; ++l) {
        const float2* gl = gmat + l * 13 * 16;

        if (l == 0) {
            // pass 0: synthesize |0..0> in registers, apply gates 0,1,2, write
            int idx[16];
            window_idx<0>(tid, idx);
            float2 v[16];
            #pragma unroll
            for (int j = 0; j < 16; ++j) v[j] = make_float2(0.f, 0.f);
            if (tid == 0) v[0] = make_float2(1.f, 0.f);
            gate_dense<0>(v, gl);
            gate_sparse<1>(v, gl + 16);
            gate_sparse<2>(v, gl + 32);
            #pragma unroll
            for (int j = 0; j < 16; ++j) st[idx[j]] = v[j];
        } else {
            pass3<0, true>(st, gl, tid);
        }
        __syncthreads();
        pass3<3, false>(st, gl + 3 * 16, tid);
        __syncthreads();
        pass3<6, false>(st, gl + 6 * 16, tid);
        __syncthreads();
        pass3<9, false>(st, gl + 9 * 16, tid);
        __syncthreads();

        // w4: gate 12 on qubits (12,13); window {10-13}, CP=2
        if (l < 2) {
            int idx[16];
            window_idx<10>(tid, idx);
            float2 v[16];
            #pragma unroll
            for (int j = 0; j < 16; ++j) v[j] = st[idx[j]];
            gate_sparse<2>(v, gl + 12 * 16);
            #pragma unroll
            for (int j = 0; j < 16; ++j) st[idx[j]] = v[j];
            __syncthreads();
        } else {
            // final pass: apply gate, emit |amp|^2 straight to global (coalesced)
            int idx[16];
            window_idx<10>(tid, idx);
            float2 v[16];
            #pragma unroll
            for (int j = 0; j < 16; ++j) v[j] = st[idx[j]];
            gate_sparse<2>(v, gl + 12 * 16);
            float* fr = feats + (size_t)b * SDIM;
            #pragma unroll
            for (int j = 0; j < 16; ++j)
                fr[tid + (j << 10)] = fmaf(v[j].x, v[j].x, v[j].y * v[j].y);
        }
    }
}

// ---------------------------------------------------------------------------
// Kernel 2: GEMM1 partials: part[bz] = feats[:, bz-chunk] @ w1[bz-chunk, :]
// M=1024, N=256, K=16384 split 8 ways. 64x64 tile, 4x4 per-thread regs.
// ---------------------------------------------------------------------------
__global__ __launch_bounds__(256) void gemm1_kernel(
    const float* __restrict__ feats,   // (1024, 16384)
    const float* __restrict__ w1,      // (16384, 256)
    float* __restrict__ part)          // (8, 1024, 256)
{
    __shared__ float As[16][68];
    __shared__ float Bs[16][68];
    const int tx = threadIdx.x & 15, ty = threadIdx.x >> 4;
    const int bx = blockIdx.x, by = blockIdx.y, bz = blockIdx.z;
    const int ml = threadIdx.x >> 2;           // 0..63  (A row)
    const int kq = (threadIdx.x & 3) << 2;     // 0,4,8,12 (A k-quad)
    const int kb = threadIdx.x >> 4;           // 0..15  (B k)
    const int nb = (threadIdx.x & 15) << 2;    // 0..60  (B col quad)

    const float* Ap = feats + (size_t)(bx * 64 + ml) * SDIM + bz * 2048;
    const float* Bp = w1 + (size_t)(bz * 2048 + kb) * 256 + by * 64 + nb;

    float acc[4][4] = {{0.f}};
    for (int kt = 0; kt < 2048; kt += 16) {
        float4 av = *(const float4*)(Ap + kt + kq);
        float4 bv = *(const float4*)(Bp + (size_t)kt * 256);
        __syncthreads();
        As[kq + 0][ml] = av.x; As[kq + 1][ml] = av.y;
        As[kq + 2][ml] = av.z; As[kq + 3][ml] = av.w;
        *(float4*)&Bs[kb][nb] = bv;
        __syncthreads();
        #pragma unroll
        for (int k = 0; k < 16; ++k) {
            float4 a  = *(const float4*)&As[k][ty << 2];
            float4 b4 = *(const float4*)&Bs[k][tx << 2];
            acc[0][0] = fmaf(a.x, b4.x, acc[0][0]); acc[0][1] = fmaf(a.x, b4.y, acc[0][1]);
            acc[0][2] = fmaf(a.x, b4.z, acc[0][2]); acc[0][3] = fmaf(a.x, b4.w, acc[0][3]);
            acc[1][0] = fmaf(a.y, b4.x, acc[1][0]); acc[1][1] = fmaf(a.y, b4.y, acc[1][1]);
            acc[1][2] = fmaf(a.y, b4.z, acc[1][2]); acc[1][3] = fmaf(a.y, b4.w, acc[1][3]);
            acc[2][0] = fmaf(a.z, b4.x, acc[2][0]); acc[2][1] = fmaf(a.z, b4.y, acc[2][1]);
            acc[2][2] = fmaf(a.z, b4.z, acc[2][2]); acc[2][3] = fmaf(a.z, b4.w, acc[2][3]);
            acc[3][0] = fmaf(a.w, b4.x, acc[3][0]); acc[3][1] = fmaf(a.w, b4.y, acc[3][1]);
            acc[3][2] = fmaf(a.w, b4.z, acc[3][2]); acc[3][3] = fmaf(a.w, b4.w, acc[3][3]);
        }
    }
    float* Cp = part + ((size_t)bz * NBATCH + bx * 64 + (ty << 2)) * 256 + by * 64 + (tx << 2);
    #pragma unroll
    for (int i = 0; i < 4; ++i)
        *(float4*)(Cp + (size_t)i * 256) = make_float4(acc[i][0], acc[i][1], acc[i][2], acc[i][3]);
}

// ---------------------------------------------------------------------------
// Kernel 3: reduce split-K partials + bias + relu, then the two small GEMMs.
// ---------------------------------------------------------------------------
__global__ __launch_bounds__(256) void tail_kernel(
    const float* __restrict__ part,  // (8, 1024, 256)
    const float* __restrict__ b1,
    const float* __restrict__ w2,    // (256, 128)
    const float* __restrict__ b2,
    const float* __restrict__ w3,    // (128, 64)
    const float* __restrict__ b3,
    float* __restrict__ out)         // (1024, 64)
{
    __shared__ float h1[256];
    __shared__ float h2[128];
    const int b = blockIdx.x, t = threadIdx.x;

    float s = b1[t];
    #pragma unroll
    for (int sp = 0; sp < 8; ++sp)
        s += part[((size_t)sp * NBATCH + b) * 256 + t];
    h1[t] = fmaxf(s, 0.f);
    __syncthreads();

    if (t < 128) {
        float acc = b2[t];
        #pragma unroll 4
        for (int k = 0; k < 256; ++k) acc = fmaf(h1[k], w2[k * 128 + t], acc);
        h2[t] = fmaxf(acc, 0.f);
    }
    __syncthreads();

    if (t < 64) {
        float acc = b3[t];
        #pragma unroll 4
        for (int k = 0; k < 128; ++k) acc = fmaf(h2[k], w3[k * 64 + t], acc);
        out[(size_t)b * 64 + t] = acc;
    }
}

// ---------------------------------------------------------------------------
extern "C" void kernel_launch(void* const* d_in, const int* in_sizes, int n_in,
                              void* d_out, int out_size, void* d_ws, size_t ws_size,
                              hipStream_t stream) {
    const float* x   = (const float*)d_in[0];
    const float* ep  = (const float*)d_in[1];
    const float* rp  = (const float*)d_in[2];
    const float* ent = (const float*)d_in[3];
    const float* w1  = (const float*)d_in[4];
    const float* b1  = (const float*)d_in[5];
    const float* w2  = (const float*)d_in[6];
    const float* b2  = (const float*)d_in[7];
    const float* w3  = (const float*)d_in[8];
    const float* b3  = (const float*)d_in[9];
    float* out = (float*)d_out;

    // ws layout: feats (1024*16384 f32 = 64 MiB) | partials (8*1024*256 f32 = 8 MiB)
    float* feats = (float*)d_ws;
    float* part  = feats + (size_t)NBATCH * SDIM;

    const int SMEM = SDIM * (int)sizeof(float2) + NGATES * 16 * (int)sizeof(float2) + 64;
    (void)hipFuncSetAttribute((const void*)sim_kernel,
                              hipFuncAttributeMaxDynamicSharedMemorySize, SMEM);

    sim_kernel<<<NBATCH, 1024, SMEM, stream>>>(x, ep, rp, ent, feats);
    gemm1_kernel<<<dim3(16, 4, 8), 256, 0, stream>>>(feats, w1, part);
    tail_kernel<<<NBATCH, 256, 0, stream>>>(part, b1, w2, b2, w3, b3, out);
}